// Round 2
// baseline (551.016 us; speedup 1.0000x reference)
//
#include <hip/hip_runtime.h>

#define R0 0.1f
#define BLOCK 256
#define CHUNK 4096   // elements per block (256 threads x 16)

// ---------------- Pass 1: per-block flag count (vectorized float4) ----------------
__global__ __launch_bounds__(BLOCK) void count_kernel(const float* __restrict__ dist,
                                                      int* __restrict__ blockCounts,
                                                      int E) {
    const int tid  = threadIdx.x;
    const int lane = tid & 63;
    const int wave = tid >> 6;
    const int E4   = E >> 2;
    const float4* d4 = reinterpret_cast<const float4*>(dist);

    int base4 = blockIdx.x * (CHUNK / 4) + tid;
    int cnt = 0;
#pragma unroll
    for (int k = 0; k < 4; ++k) {
        int i4 = base4 + k * BLOCK;
        if (i4 < E4) {
            float4 v = d4[i4];
            cnt += (v.x < R0) + (v.y < R0) + (v.z < R0) + (v.w < R0);
        }
    }
    // wave reduce
#pragma unroll
    for (int off = 32; off > 0; off >>= 1) cnt += __shfl_down(cnt, off, 64);
    __shared__ int wcnt[4];
    if (lane == 0) wcnt[wave] = cnt;
    __syncthreads();
    if (tid == 0) blockCounts[blockIdx.x] = wcnt[0] + wcnt[1] + wcnt[2] + wcnt[3];
}

// ---------------- Pass 2: exclusive scan over block counts (single block) ----------------
// Assumes nblocks <= 8192 (E <= 33.5M). 256 threads x 32 counts each.
__global__ __launch_bounds__(BLOCK) void scan_kernel(const int* __restrict__ blockCounts,
                                                     int* __restrict__ blockOffsets,
                                                     int nblocks,
                                                     int* __restrict__ totalOut) {
    const int tid  = threadIdx.x;
    const int lane = tid & 63;
    const int wave = tid >> 6;
    const int start = tid * 32;

    int cnts[32];
    int sum = 0;
#pragma unroll
    for (int j = 0; j < 32; ++j) {
        int b = start + j;
        int c = (b < nblocks) ? blockCounts[b] : 0;
        cnts[j] = c;
        sum += c;
    }
    // inclusive scan of `sum` within wave
    int v = sum;
#pragma unroll
    for (int off = 1; off < 64; off <<= 1) {
        int n = __shfl_up(v, off, 64);
        if (lane >= off) v += n;
    }
    __shared__ int wtot[4], wpre[4];
    if (lane == 63) wtot[wave] = v;
    __syncthreads();
    if (tid == 0) {
        int r = 0;
        for (int w = 0; w < 4; ++w) { wpre[w] = r; r += wtot[w]; }
        *totalOut = r;  // n_edges
    }
    __syncthreads();
    int run = (v - sum) + wpre[wave];  // exclusive prefix for this thread
#pragma unroll
    for (int j = 0; j < 32; ++j) {
        int b = start + j;
        if (b < nblocks) blockOffsets[b] = run;
        run += cnts[j];
    }
}

// ---------------- Pass 3: stable scatter ----------------
__global__ __launch_bounds__(BLOCK) void scatter_kernel(const float* __restrict__ dist,
                                                        const int2* __restrict__ edges,
                                                        const int* __restrict__ blockOffsets,
                                                        int* __restrict__ src,
                                                        int* __restrict__ dst,
                                                        int E) {
    const int tid  = threadIdx.x;
    const int lane = tid & 63;
    const int wave = tid >> 6;
    const int base = blockIdx.x * CHUNK;
    const int waveBase = base + wave * 1024;   // each wave owns 1024 contiguous elems

    unsigned long long masks[16];
    int wcount = 0;
#pragma unroll
    for (int k = 0; k < 16; ++k) {
        int i = waveBase + k * 64 + lane;
        float d = (i < E) ? dist[i] : 1.0f;
        unsigned long long m = __ballot(d < R0);
        masks[k] = m;
        wcount += __popcll(m);
    }
    __shared__ int wtot[4], wpre[4];
    if (lane == 0) wtot[wave] = wcount;
    __syncthreads();
    if (tid == 0) {
        int r = 0;
        for (int w = 0; w < 4; ++w) { wpre[w] = r; r += wtot[w]; }
    }
    __syncthreads();

    int run = blockOffsets[blockIdx.x] + wpre[wave];
    const unsigned long long lanemask_lt = (lane == 0) ? 0ull : (~0ull >> (64 - lane));
#pragma unroll
    for (int k = 0; k < 16; ++k) {
        unsigned long long m = masks[k];
        int i = waveBase + k * 64 + lane;
        if ((m >> lane) & 1ull) {
            int pos = run + __popcll(m & lanemask_lt);
            int2 e = edges[i];
            src[pos] = e.x;
            dst[pos] = e.y;
        }
        run += __popcll(m);
    }
}

extern "C" void kernel_launch(void* const* d_in, const int* in_sizes, int n_in,
                              void* d_out, int out_size, void* d_ws, size_t ws_size,
                              hipStream_t stream) {
    const float* dist = (const float*)d_in[0];
    const int2*  edges = (const int2*)d_in[1];
    const int E = in_sizes[0];

    int* out   = (int*)d_out;
    int* src   = out;
    int* dst   = out + (size_t)E;
    int* total = out + (size_t)2 * E;

    const int nblocks = (E + CHUNK - 1) / CHUNK;
    int* blockCounts  = (int*)d_ws;
    int* blockOffsets = blockCounts + nblocks;

    // Fill src/dst with -1 (tail padding); compacted prefix overwritten by scatter.
    hipMemsetAsync(d_out, 0xFF, (size_t)2 * E * sizeof(int), stream);

    count_kernel<<<nblocks, BLOCK, 0, stream>>>(dist, blockCounts, E);
    scan_kernel<<<1, BLOCK, 0, stream>>>(blockCounts, blockOffsets, nblocks, total);
    scatter_kernel<<<nblocks, BLOCK, 0, stream>>>(dist, edges, blockOffsets, src, dst, E);
}

// Round 5
// 528.494 us; speedup vs baseline: 1.0426x; 1.0426x over previous
//
#include <hip/hip_runtime.h>

#define R0 0.1f
#define BLOCK 256
#define CHUNK 4096   // elements per block

typedef unsigned long long u64;
typedef int int4v __attribute__((ext_vector_type(4)));   // native vector for nontemporal store

// ---------------- Pass 1: count + ballot-mask store (float4 loads) ----------------
// Element (blk, k, wave, lane, j) = blk*4096 + k*1024 + wave*256 + 4*lane + j
// Mask layout: maskBuf[((blk*4 + k)*4 + wave)*4 + j], bit L = element ... + 4L + j
__global__ __launch_bounds__(BLOCK) void count_mask_kernel(const float* __restrict__ dist,
                                                           int* __restrict__ blockCounts,
                                                           u64* __restrict__ maskBuf,
                                                           int E) {
    const int tid  = threadIdx.x;
    const int lane = tid & 63;
    const int wave = tid >> 6;
    const int E4   = E >> 2;           // E is a multiple of 4 in this problem
    const float4* d4 = reinterpret_cast<const float4*>(dist);
    const int blk = blockIdx.x;

    __shared__ int wcnt[4];
    int mycnt = 0;
#pragma unroll
    for (int k = 0; k < 4; ++k) {
        int i4 = blk * (CHUNK / 4) + k * BLOCK + tid;
        float4 v = make_float4(1.f, 1.f, 1.f, 1.f);
        if (i4 < E4) v = d4[i4];
        u64 b0 = __ballot(v.x < R0);
        u64 b1 = __ballot(v.y < R0);
        u64 b2 = __ballot(v.z < R0);
        u64 b3 = __ballot(v.w < R0);
        u64* mptr = maskBuf + (((size_t)blk * 4 + k) * 4 + wave) * 4;
        if (lane == 0) { mptr[0] = b0; mptr[1] = b1; mptr[2] = b2; mptr[3] = b3; }
        mycnt += __popcll(b0) + __popcll(b1) + __popcll(b2) + __popcll(b3);
    }
    if (lane == 0) wcnt[wave] = mycnt;
    __syncthreads();
    if (tid == 0) blockCounts[blk] = wcnt[0] + wcnt[1] + wcnt[2] + wcnt[3];
}

// ---------------- Pass 2: exclusive scan over block counts (single block) ----------------
// nblocks <= 8192 (256 threads x 32 each)
__global__ __launch_bounds__(BLOCK) void scan_kernel(const int* __restrict__ blockCounts,
                                                     int* __restrict__ blockOffsets,
                                                     int nblocks,
                                                     int* __restrict__ totalOut) {
    const int tid  = threadIdx.x;
    const int lane = tid & 63;
    const int wave = tid >> 6;
    const int start = tid * 32;

    int cnts[32];
    int sum = 0;
#pragma unroll
    for (int j = 0; j < 32; ++j) {
        int b = start + j;
        int c = (b < nblocks) ? blockCounts[b] : 0;
        cnts[j] = c;
        sum += c;
    }
    int v = sum;
#pragma unroll
    for (int off = 1; off < 64; off <<= 1) {
        int n = __shfl_up(v, off, 64);
        if (lane >= off) v += n;
    }
    __shared__ int wtot[4], wpre[4];
    if (lane == 63) wtot[wave] = v;
    __syncthreads();
    if (tid == 0) {
        int r = 0;
        for (int w = 0; w < 4; ++w) { wpre[w] = r; r += wtot[w]; }
        *totalOut = r;   // n_edges -> d_out[2E]
    }
    __syncthreads();
    int run = (v - sum) + wpre[wave];
#pragma unroll
    for (int j = 0; j < 32; ++j) {
        int b = start + j;
        if (b < nblocks) blockOffsets[b] = run;
        run += cnts[j];
    }
}

// ---------------- Pass 3: stable scatter from masks + fused tail-fill ----------------
__global__ __launch_bounds__(BLOCK) void scatter_kernel(const int2* __restrict__ edges,
                                                        const u64* __restrict__ maskBuf,
                                                        const int* __restrict__ blockOffsets,
                                                        const int* __restrict__ totalPtr,
                                                        int* __restrict__ src,
                                                        int* __restrict__ dst,
                                                        int E) {
    const int tid  = threadIdx.x;
    const int lane = tid & 63;
    const int wave = tid >> 6;
    const int blk  = blockIdx.x;
    const int base = blk * CHUNK;
    const int nE   = *totalPtr;    // uniform broadcast load

    // ---- tail fill: output positions p in [base, base+CHUNK) with p >= nE get -1
    if (base + CHUNK > nE) {
        const int4v m1 = {-1, -1, -1, -1};
#pragma unroll
        for (int t = 0; t < 4; ++t) {
            int p = base + t * (BLOCK * 4) + tid * 4;
            if (p >= nE) {
                __builtin_nontemporal_store(m1, (int4v*)(src + p));
                __builtin_nontemporal_store(m1, (int4v*)(dst + p));
            } else if (p + 4 > nE) {
#pragma unroll
                for (int j = 0; j < 4; ++j)
                    if (p + j >= nE) { src[p + j] = -1; dst[p + j] = -1; }
            }
        }
    }

    // ---- load masks, per-(k,wave) counts
    u64 b[4][4];
    __shared__ int cnt[4][4];   // [k][wave]
#pragma unroll
    for (int k = 0; k < 4; ++k) {
        const u64* mptr = maskBuf + (((size_t)blk * 4 + k) * 4 + wave) * 4;
        b[k][0] = mptr[0]; b[k][1] = mptr[1]; b[k][2] = mptr[2]; b[k][3] = mptr[3];
        if (lane == 0)
            cnt[k][wave] = __popcll(b[k][0]) + __popcll(b[k][1]) +
                           __popcll(b[k][2]) + __popcll(b[k][3]);
    }
    __syncthreads();

    // exclusive prefix over (k, wave) in element order (k outer, wave inner)
    int mypre[4];
    {
        int acc = 0;
#pragma unroll
        for (int kk = 0; kk < 4; ++kk) {
#pragma unroll
            for (int w = 0; w < 4; ++w) {
                if (w == wave) mypre[kk] = acc;
                acc += cnt[kk][w];
            }
        }
    }

    const int run = blockOffsets[blk];
    const u64 lt = (lane == 0) ? 0ull : (~0ull >> (64 - lane));
#pragma unroll
    for (int k = 0; k < 4; ++k) {
        int rlane = run + mypre[k] +
                    __popcll(b[k][0] & lt) + __popcll(b[k][1] & lt) +
                    __popcll(b[k][2] & lt) + __popcll(b[k][3] & lt);
        int e0 = base + k * 1024 + wave * 256 + lane * 4;
        int f0 = (int)((b[k][0] >> lane) & 1ull);
        int f1 = (int)((b[k][1] >> lane) & 1ull);
        int f2 = (int)((b[k][2] >> lane) & 1ull);
        int f3 = (int)((b[k][3] >> lane) & 1ull);
        if (f0) { int2 e = edges[e0];     src[rlane] = e.x;            dst[rlane] = e.y; }
        if (f1) { int2 e = edges[e0 + 1]; int p = rlane + f0;          src[p] = e.x; dst[p] = e.y; }
        if (f2) { int2 e = edges[e0 + 2]; int p = rlane + f0 + f1;     src[p] = e.x; dst[p] = e.y; }
        if (f3) { int2 e = edges[e0 + 3]; int p = rlane + f0 + f1 + f2; src[p] = e.x; dst[p] = e.y; }
    }
}

extern "C" void kernel_launch(void* const* d_in, const int* in_sizes, int n_in,
                              void* d_out, int out_size, void* d_ws, size_t ws_size,
                              hipStream_t stream) {
    const float* dist  = (const float*)d_in[0];
    const int2*  edges = (const int2*)d_in[1];
    const int E = in_sizes[0];

    int* out   = (int*)d_out;
    int* src   = out;
    int* dst   = out + (size_t)E;
    int* total = out + (size_t)2 * E;   // n_edges scalar (written by scan)

    const int nblocks = (E + CHUNK - 1) / CHUNK;

    // workspace layout: [blockCounts nblocks][blockOffsets nblocks][pad][masks]
    int* blockCounts  = (int*)d_ws;
    int* blockOffsets = blockCounts + nblocks;
    u64* maskBuf      = (u64*)(blockOffsets + nblocks + 2);  // 8B-aligned (nblocks even)

    count_mask_kernel<<<nblocks, BLOCK, 0, stream>>>(dist, blockCounts, maskBuf, E);
    scan_kernel<<<1, BLOCK, 0, stream>>>(blockCounts, blockOffsets, nblocks, total);
    scatter_kernel<<<nblocks, BLOCK, 0, stream>>>(edges, maskBuf, blockOffsets, total, src, dst, E);
}